// Round 4
// baseline (553.407 us; speedup 1.0000x reference)
//
#include <hip/hip_runtime.h>

#define B_  2048
#define S_  512
#define F_  64
#define H_  32
#define G_  128   // 4*H
#define D_  6     // x-tile prefetch depth (ring of 8)

__device__ __forceinline__ void gload_lds4(const float* g, float* l) {
    __builtin_amdgcn_global_load_lds(
        (const __attribute__((address_space(1))) void*)g,
        (__attribute__((address_space(3))) void*)l,
        4, 0, 0);
}

// Arch-VGPR-pinned FMA: acc += a * b
#define FMAC(acc, a, b) asm("v_fmac_f32 %0, %1, %2" : "+v"(acc) : "v"(a), "v"(b))

// wave0 owns gate columns {i, g}; wave1 owns {f, o}.
__global__ __launch_bounds__(128, 4)
void lstm_mlp_kernel(const float* __restrict__ x,
                     const float* __restrict__ Wx,
                     const float* __restrict__ Wh,
                     const float* __restrict__ bg,
                     const float* __restrict__ W1,
                     const float* __restrict__ b1,
                     const float* __restrict__ W2,
                     const float* __restrict__ b2,
                     const float* __restrict__ Wo,
                     const float* __restrict__ bo,
                     float* __restrict__ out)
{
    const int tid  = threadIdx.x;    // 0..127
    const int wid  = tid >> 6;
    const int lane = tid & 63;
    const int hi   = lane >> 5;      // 0: lanes 0..31, 1: lanes 32..63
    // gate column: i:0..31 f:32..63 g:64..95 o:96..127
    const int gcol = lane + ((wid + hi) << 5);
    const int b    = blockIdx.x;

    __shared__ float xring[8][64];
    __shared__ float hb[2][32];      // per-wave private copy of h
    __shared__ float igb[2][32];     // i*g, parity double-buffered
    __shared__ float fob[2][32][2];  // {f, o} pairs, parity double-buffered

    // ---- register-resident weight column (96 arch VGPRs/lane) ----
    float wx[F_];
#pragma unroll
    for (int f = 0; f < F_; ++f) wx[f] = Wx[f * G_ + gcol];
    float wh[H_];
#pragma unroll
    for (int k = 0; k < H_; ++k) wh[k] = Wh[k * G_ + gcol];
    const float bz = bg[gcol];

    const float* xb = x + (size_t)b * (S_ * F_);

    if (hi == 0) hb[wid][lane] = 0.0f;   // h_0 = 0 (wave-local copy)
    if (wid == 0) {
        for (int t = 0; t < D_; ++t)
            gload_lds4(xb + t * F_ + lane, &xring[t][0]);
        asm volatile("s_waitcnt vmcnt(5)" ::: "memory");   // tile 0 landed
    }
    __syncthreads();

    float cc = 0.0f;   // cell state, lanes 0..31 of BOTH waves (duplicated)

    for (int t = 0; t < S_; ++t) {
        const float4* xt = (const float4*)&xring[t & 7][0];
        const float4* hp = (const float4*)&hb[wid][0];
        const int par = t & 1;

        float z0 = bz, z1 = 0.0f;
#pragma unroll
        for (int q = 0; q < 8; ++q) {          // recurrent part: 32 FMAs
            float4 h4 = hp[q];
            FMAC(z0, h4.x, wh[4 * q + 0]);
            FMAC(z1, h4.y, wh[4 * q + 1]);
            FMAC(z0, h4.z, wh[4 * q + 2]);
            FMAC(z1, h4.w, wh[4 * q + 3]);
        }
#pragma unroll
        for (int q = 0; q < 16; ++q) {         // input part: 64 FMAs
            float4 x4 = xt[q];
            FMAC(z0, x4.x, wx[4 * q + 0]);
            FMAC(z1, x4.y, wx[4 * q + 1]);
            FMAC(z0, x4.z, wx[4 * q + 2]);
            FMAC(z1, x4.w, wx[4 * q + 3]);
        }
        float z = z0 + z1;

        // nonlinearity: tanh only for wave0 upper half (g); sigmoid otherwise
        const bool istanh = (wid == 0) && (hi == 1);
        float zx = istanh ? 2.0f * z : z;
        float s  = __builtin_amdgcn_rcpf(1.0f + __expf(-zx));
        float r  = istanh ? 2.0f * s - 1.0f : s;

        // in-wave gate pairing
        float rsh = __shfl_xor(r, 32);
        if (wid == 0) {
            if (hi == 0) igb[par][lane] = r * rsh;        // i * g
        } else {
            if (hi == 0) { fob[par][lane][0] = r;         // f
                           fob[par][lane][1] = rsh; }     // o
        }

        // prefetch tile t+D (clamped re-issue keeps vmcnt constant)
        if (wid == 0) {
            int tp = t + D_; if (tp > S_ - 1) tp = S_ - 1;
            gload_lds4(xb + tp * F_ + lane, &xring[(t + D_) & 7][0]);
            asm volatile("s_waitcnt vmcnt(5)" ::: "memory");  // tile t+1 landed
        }
        __syncthreads();   // publishes igb/fob(par) and xring[t+1]

        // combine, duplicated in both waves (lanes 0..31)
        if (hi == 0) {
            float igv = igb[par][lane];
            float fv  = fob[par][lane][0];
            float ov  = fob[par][lane][1];
            cc = fmaf(fv, cc, igv);                        // c = f*c + i*g
            float th = 2.0f * __builtin_amdgcn_rcpf(1.0f + __expf(-2.0f * cc)) - 1.0f;
            hb[wid][lane] = ov * th;                       // h = o * tanh(c)
        }
    }
    __syncthreads();

    // ---- MLP head: 32 -> 32 -> 16 -> 3, leaky_relu(0.01) ----
    if (tid < 32) {
        float a1 = b1[tid];
#pragma unroll
        for (int k = 0; k < 32; ++k)
            a1 = fmaf(hb[0][k], W1[k * 32 + tid], a1);
        a1 = (a1 > 0.0f) ? a1 : 0.01f * a1;
        igb[0][tid] = a1;
    }
    __syncthreads();
    if (tid < 16) {
        float a2 = b2[tid];
#pragma unroll
        for (int k = 0; k < 32; ++k)
            a2 = fmaf(igb[0][k], W2[k * 16 + tid], a2);
        a2 = (a2 > 0.0f) ? a2 : 0.01f * a2;
        fob[0][tid][0] = a2;
    }
    __syncthreads();
    if (tid < 3) {
        float o = bo[tid];
#pragma unroll
        for (int k = 0; k < 16; ++k)
            o = fmaf(fob[0][k][0], Wo[k * 3 + tid], o);
        out[(size_t)b * 3 + tid] = o;
    }
}

extern "C" void kernel_launch(void* const* d_in, const int* in_sizes, int n_in,
                              void* d_out, int out_size, void* d_ws, size_t ws_size,
                              hipStream_t stream) {
    const float* x  = (const float*)d_in[0];
    const float* Wx = (const float*)d_in[1];
    const float* Wh = (const float*)d_in[2];
    const float* bg = (const float*)d_in[3];
    const float* W1 = (const float*)d_in[4];
    const float* b1 = (const float*)d_in[5];
    const float* W2 = (const float*)d_in[6];
    const float* b2 = (const float*)d_in[7];
    const float* Wo = (const float*)d_in[8];
    const float* bo = (const float*)d_in[9];
    float* out = (float*)d_out;

    hipLaunchKernelGGL(lstm_mlp_kernel, dim3(B_), dim3(128), 0, stream,
                       x, Wx, Wh, bg, W1, b1, W2, b2, Wo, bo, out);
}

// Round 5
// 354.993 us; speedup vs baseline: 1.5589x; 1.5589x over previous
//
#include <hip/hip_runtime.h>

#define S_  512
#define F_  64
#define H_  32
#define GQ  128   // 4*H
#define BT  16    // batch rows per block
#define NB  128   // 2048/BT

typedef __attribute__((ext_vector_type(8))) short bf16x8;
typedef __attribute__((ext_vector_type(4))) float f32x4;

struct Frag { bf16x8 h, l; };

// f32 -> (bf16_hi << 16) | bf16_lo, both RNE; f ~= hi + lo with ~2^-17 rel err
__device__ __forceinline__ unsigned pack_split(float f) {
    unsigned u  = __builtin_bit_cast(unsigned, f);
    unsigned hi = (u + 0x7FFFu + ((u >> 16) & 1u)) & 0xFFFF0000u;
    float    fl = f - __builtin_bit_cast(float, hi);
    unsigned ul = __builtin_bit_cast(unsigned, fl);
    unsigned lo = (ul + 0x7FFFu + ((ul >> 16) & 1u)) >> 16;
    return hi | lo;
}

// two uint4 of packed u32 -> hi-frag and lo-frag (8 bf16 each)
__device__ __forceinline__ Frag unpack_frag2(uint4 a, uint4 b) {
    uint4 hh, ll;
    hh.x = __builtin_amdgcn_perm(a.y, a.x, 0x07060302u);
    hh.y = __builtin_amdgcn_perm(a.w, a.z, 0x07060302u);
    hh.z = __builtin_amdgcn_perm(b.y, b.x, 0x07060302u);
    hh.w = __builtin_amdgcn_perm(b.w, b.z, 0x07060302u);
    ll.x = __builtin_amdgcn_perm(a.y, a.x, 0x05040100u);
    ll.y = __builtin_amdgcn_perm(a.w, a.z, 0x05040100u);
    ll.z = __builtin_amdgcn_perm(b.y, b.x, 0x05040100u);
    ll.w = __builtin_amdgcn_perm(b.w, b.z, 0x05040100u);
    Frag r;
    r.h = __builtin_bit_cast(bf16x8, hh);
    r.l = __builtin_bit_cast(bf16x8, ll);
    return r;
}

__device__ __forceinline__ Frag unpack_arr(const unsigned p[8]) {
    uint4 a = { p[0], p[1], p[2], p[3] };
    uint4 b = { p[4], p[5], p[6], p[7] };
    return unpack_frag2(a, b);
}

#define MFMA(A, B, C) __builtin_amdgcn_mfma_f32_16x16x32_bf16(A, B, C, 0, 0, 0)

__global__ __launch_bounds__(512, 1)
void lstm_mfma_kernel(const float* __restrict__ x,  const float* __restrict__ Wx,
                      const float* __restrict__ Wh, const float* __restrict__ bg,
                      const float* __restrict__ W1, const float* __restrict__ b1,
                      const float* __restrict__ W2, const float* __restrict__ b2,
                      const float* __restrict__ Wo, const float* __restrict__ bo,
                      float* __restrict__ out)
{
    const int tid = threadIdx.x;     // 0..511
    const int wid = tid >> 6;        // n-tile owner: gate cols 16w..16w+15
    const int L   = tid & 63;
    const int c16 = L & 15;          // col within n-tile / A-row (batch)
    const int kg  = L >> 4;          // k-group (8 contiguous k per group)
    const int bb  = blockIdx.x * BT;

    __shared__ unsigned xp[4][BT][68];   // packed-split x, ring of 4 steps (padded)
    __shared__ unsigned hp[BT][36];      // packed-split h (padded)
    __shared__ float    Gp[4][BT][33];   // gate planes i,f,g,o (padded)

    const int gc = (wid << 4) + c16;     // global gate column 0..127

    // ---- B-fragments: Wh and Wx columns, split into hi/lo bf16 (once) ----
    unsigned pk[8];
#pragma unroll
    for (int i = 0; i < 8; ++i) pk[i] = pack_split(Wh[(kg * 8 + i) * GQ + gc]);
    Frag whf = unpack_arr(pk);
#pragma unroll
    for (int i = 0; i < 8; ++i) pk[i] = pack_split(Wx[(kg * 8 + i) * GQ + gc]);
    Frag wx0 = unpack_arr(pk);
#pragma unroll
    for (int i = 0; i < 8; ++i) pk[i] = pack_split(Wx[(32 + kg * 8 + i) * GQ + gc]);
    Frag wx1 = unpack_arr(pk);

    const float bzv = bg[gc];
    const f32x4 biasC = { bzv, bzv, bzv, bzv };

    // combine-cell ownership: one (b, j) cell per thread
    const int cb = tid >> 5;   // batch row 0..15
    const int cj = tid & 31;   // hidden unit 0..31

    // zero h_0
    for (int i = tid; i < BT * 36; i += 512) (&hp[0][0])[i] = 0u;

    // prologue: pack x for t = 0, 1
    const float* xrow = x + (size_t)(bb + cb) * S_ * F_ + 2 * cj;
#pragma unroll
    for (int tt = 0; tt < 2; ++tt) {
        float2 xv = *(const float2*)(xrow + tt * F_);
        xp[tt][cb][2 * cj]     = pack_split(xv.x);
        xp[tt][cb][2 * cj + 1] = pack_split(xv.y);
    }

    float cc = 0.0f, hlast = 0.0f;
    const bool is_tanh = (wid == 4) || (wid == 5);

    for (int t = 0; t < S_; ++t) {
        __syncthreads();   // A: hp (h_{t-1}) and xp[t&3] ready

        // prefetch x for t+2 (consumed at end of this iteration)
        float2 xnext = {0.0f, 0.0f};
        if (t < S_ - 2) xnext = *(const float2*)(xrow + (size_t)(t + 2) * F_);

        // A-fragments: row = c16 (batch), k = kg*8 + i
        const uint4* hq = (const uint4*)&hp[c16][kg * 8];
        Frag ah = unpack_frag2(hq[0], hq[1]);
        const uint4* xq0 = (const uint4*)&xp[t & 3][c16][kg * 8];
        Frag ax0 = unpack_frag2(xq0[0], xq0[1]);
        const uint4* xq1 = (const uint4*)&xp[t & 3][c16][32 + kg * 8];
        Frag ax1 = unpack_frag2(xq1[0], xq1[1]);

        // z = bias + x_t @ Wx + h @ Wh   (3-term bf16-split per product)
        f32x4 acc = biasC;
        acc = MFMA(ax0.h, wx0.h, acc);
        acc = MFMA(ax0.l, wx0.h, acc);
        acc = MFMA(ax0.h, wx0.l, acc);
        acc = MFMA(ax1.h, wx1.h, acc);
        acc = MFMA(ax1.l, wx1.h, acc);
        acc = MFMA(ax1.h, wx1.l, acc);
        acc = MFMA(ah.h,  whf.h, acc);
        acc = MFMA(ah.l,  whf.h, acc);
        acc = MFMA(ah.h,  whf.l, acc);

        // nonlinearity (wave-uniform type) + publish gates
        const int jw = ((wid & 1) << 4) + c16;
#pragma unroll
        for (int r = 0; r < 4; ++r) {
            float v  = acc[r];
            float zx = is_tanh ? 2.0f * v : v;
            float s  = __builtin_amdgcn_rcpf(1.0f + __expf(-zx));
            float g  = is_tanh ? 2.0f * s - 1.0f : s;
            Gp[wid >> 1][kg * 4 + r][jw] = g;   // D row = kg*4 + r
        }
        __syncthreads();   // B: gates ready

        // combine (one cell per thread; c persistent in VGPR)
        float iv = Gp[0][cb][cj];
        float fv = Gp[1][cb][cj];
        float gv = Gp[2][cb][cj];
        float ov = Gp[3][cb][cj];
        cc = fmaf(fv, cc, iv * gv);
        float th = 2.0f * __builtin_amdgcn_rcpf(1.0f + __expf(-2.0f * cc)) - 1.0f;
        hlast = ov * th;
        hp[cb][cj] = pack_split(hlast);
        if (t < S_ - 2) {
            xp[(t + 2) & 3][cb][2 * cj]     = pack_split(xnext.x);
            xp[(t + 2) & 3][cb][2 * cj + 1] = pack_split(xnext.y);
        }
    }
    __syncthreads();

    // ---- MLP head: 32 -> 32 -> 16 -> 3, leaky_relu(0.01) ----
    float* Hb = &Gp[0][0][0];
    Hb[cb * 33 + cj] = hlast;
    __syncthreads();
    float* A1 = &Gp[1][0][0];
    {
        int n = tid & 31, rb = tid >> 5;
        float a = b1[n];
#pragma unroll
        for (int k = 0; k < 32; ++k) a = fmaf(Hb[rb * 33 + k], W1[k * 32 + n], a);
        a = (a > 0.0f) ? a : 0.01f * a;
        A1[rb * 33 + n] = a;
    }
    __syncthreads();
    float* A2 = &Gp[2][0][0];
    if ((tid & 31) < 16) {
        int n = tid & 31, rb = tid >> 5;
        float a = b2[n];
#pragma unroll
        for (int k = 0; k < 32; ++k) a = fmaf(A1[rb * 33 + k], W2[k * 16 + n], a);
        a = (a > 0.0f) ? a : 0.01f * a;
        A2[rb * 33 + n] = a;
    }
    __syncthreads();
    if ((tid & 31) < 3) {
        int n = tid & 31, rb = tid >> 5;
        float a = bo[n];
#pragma unroll
        for (int k = 0; k < 16; ++k) a = fmaf(A2[rb * 33 + k], Wo[k * 3 + n], a);
        out[(size_t)(bb + rb) * 3 + n] = a;
    }
}

extern "C" void kernel_launch(void* const* d_in, const int* in_sizes, int n_in,
                              void* d_out, int out_size, void* d_ws, size_t ws_size,
                              hipStream_t stream) {
    const float* x  = (const float*)d_in[0];
    const float* Wx = (const float*)d_in[1];
    const float* Wh = (const float*)d_in[2];
    const float* bg = (const float*)d_in[3];
    const float* W1 = (const float*)d_in[4];
    const float* b1 = (const float*)d_in[5];
    const float* W2 = (const float*)d_in[6];
    const float* b2 = (const float*)d_in[7];
    const float* Wo = (const float*)d_in[8];
    const float* bo = (const float*)d_in[9];
    float* out = (float*)d_out;

    hipLaunchKernelGGL(lstm_mfma_kernel, dim3(NB), dim3(512), 0, stream,
                       x, Wx, Wh, bg, W1, b1, W2, b2, Wo, bo, out);
}

// Round 6
// 309.737 us; speedup vs baseline: 1.7867x; 1.1461x over previous
//
#include <hip/hip_runtime.h>

#define S_  512
#define F_  64
#define H_  32
#define GQ  128   // 4*H
#define BT  8     // batch rows per block
#define NB  256   // 2048/BT  -> one block per CU

#define XS  72    // x plane row stride (ushorts): b128 quad-slots uniform
#define HS  40    // h plane row stride (ushorts): b128 quad-slots uniform
#define GS  34    // gate plane row stride (floats): 2-way (free)

typedef __attribute__((ext_vector_type(8))) short bf16x8;
typedef __attribute__((ext_vector_type(4))) float f32x4;

// f32 -> (bf16_hi << 16) | bf16_lo, both RNE; f ~= hi + lo with ~2^-17 rel err
__device__ __forceinline__ unsigned pack_split(float f) {
    unsigned u  = __builtin_bit_cast(unsigned, f);
    unsigned hi = (u + 0x7FFFu + ((u >> 16) & 1u)) & 0xFFFF0000u;
    float    fl = f - __builtin_bit_cast(float, hi);
    unsigned ul = __builtin_bit_cast(unsigned, fl);
    unsigned lo = (ul + 0x7FFFu + ((ul >> 16) & 1u)) >> 16;
    return hi | lo;
}

#define MFMA(A, B, C) __builtin_amdgcn_mfma_f32_16x16x32_bf16(A, B, C, 0, 0, 0)

__global__ __launch_bounds__(512, 1)
void lstm_mfma_kernel(const float* __restrict__ x,  const float* __restrict__ Wx,
                      const float* __restrict__ Wh, const float* __restrict__ bg,
                      const float* __restrict__ W1, const float* __restrict__ b1,
                      const float* __restrict__ W2, const float* __restrict__ b2,
                      const float* __restrict__ Wo, const float* __restrict__ bo,
                      float* __restrict__ out)
{
    const int tid = threadIdx.x;     // 0..511
    const int wid = tid >> 6;        // gate cols 16*wid .. 16*wid+15
    const int L   = tid & 63;
    const int c16 = L & 15;          // A row (batch) / B col
    const int kg  = L >> 4;          // k-group (8 contiguous k)
    const int bb  = blockIdx.x * BT;

    // hi/lo bf16 planes (rows 8..15 stay zero: finite garbage discarded)
    __shared__ __align__(16) unsigned short xh[4][16][XS], xl[4][16][XS];
    __shared__ __align__(16) unsigned short hh[16][HS],    hl[16][HS];
    __shared__ float Gp[4][16][GS];      // gate planes i,f,g,o

    const int gc = (wid << 4) + c16;     // global gate column

    // ---- B fragments: direct bf16 split, no perms ----
    bf16x8 whh_, whl_, wx0h, wx0l, wx1h, wx1l;
#pragma unroll
    for (int i = 0; i < 8; ++i) {
        unsigned p = pack_split(Wh[(kg * 8 + i) * GQ + gc]);
        whh_[i] = (short)(unsigned short)(p >> 16);
        whl_[i] = (short)(unsigned short)(p & 0xFFFFu);
        p = pack_split(Wx[(kg * 8 + i) * GQ + gc]);
        wx0h[i] = (short)(unsigned short)(p >> 16);
        wx0l[i] = (short)(unsigned short)(p & 0xFFFFu);
        p = pack_split(Wx[(32 + kg * 8 + i) * GQ + gc]);
        wx1h[i] = (short)(unsigned short)(p >> 16);
        wx1l[i] = (short)(unsigned short)(p & 0xFFFFu);
    }
    const float bzv = bg[gc];
    const f32x4 biasC = { bzv, bzv, bzv, bzv };

    // role split
    const int cb = tid >> 5, cj = tid & 31;            // combine cell (tid<256)
    const int u  = (tid >= 256) ? tid - 256 : 0;
    const int pr = u >> 5, pc = (u & 31) * 2;          // prefetch row/col (tid>=256)
    const float* xsrc = x + (size_t)(bb + pr) * S_ * F_ + pc;

    // ---- zero-init: x planes rows 8..15 (all slots); h planes fully ----
    for (int i = tid; i < 4 * 8 * (XS / 2); i += 512) {
        int slot = i / (8 * (XS / 2));
        int rem  = i - slot * 8 * (XS / 2);
        int row  = 8 + rem / (XS / 2);
        int col  = rem % (XS / 2);
        ((unsigned*)&xh[slot][row][0])[col] = 0u;
        ((unsigned*)&xl[slot][row][0])[col] = 0u;
    }
    for (int i = tid; i < 16 * (HS / 2); i += 512) {
        ((unsigned*)&hh[0][0])[i] = 0u;
        ((unsigned*)&hl[0][0])[i] = 0u;
    }
    // prologue: fill x slots 0,1 (rows 0..7)
    if (tid >= 256) {
#pragma unroll
        for (int tt = 0; tt < 2; ++tt) {
            float2 xv = *(const float2*)(xsrc + (size_t)tt * F_);
            unsigned p0 = pack_split(xv.x), p1 = pack_split(xv.y);
            *(unsigned*)&xh[tt][pr][pc] = (p0 >> 16) | (p1 & 0xFFFF0000u);
            *(unsigned*)&xl[tt][pr][pc] = (p0 & 0xFFFFu) | (p1 << 16);
        }
    }

    float cc = 0.0f, hlast = 0.0f;
    const bool is_tanh = (wid == 4) || (wid == 5);
    const int jw = ((wid & 1) << 4) + c16;

    for (int t = 0; t < S_; ++t) {
        __syncthreads();   // A: h and x[t&3] ready

        float2 xnext;
        const bool doPre = (tid >= 256) && (t + 2 < S_);
        if (doPre) xnext = *(const float2*)(xsrc + (size_t)(t + 2) * F_);

        // A fragments: direct b128 reads, no unpack
        const int xs = t & 3;
        bf16x8 ah_h = *(const bf16x8*)&hh[c16][kg * 8];
        bf16x8 ah_l = *(const bf16x8*)&hl[c16][kg * 8];
        bf16x8 ax0h = *(const bf16x8*)&xh[xs][c16][kg * 8];
        bf16x8 ax0l = *(const bf16x8*)&xl[xs][c16][kg * 8];
        bf16x8 ax1h = *(const bf16x8*)&xh[xs][c16][32 + kg * 8];
        bf16x8 ax1l = *(const bf16x8*)&xl[xs][c16][32 + kg * 8];

        // 3 independent chains of 3 MFMAs
        f32x4 a0 = biasC;
        f32x4 a1 = { 0.0f, 0.0f, 0.0f, 0.0f };
        f32x4 a2 = { 0.0f, 0.0f, 0.0f, 0.0f };
        a0 = MFMA(ax0h, wx0h, a0);
        a1 = MFMA(ax0l, wx0h, a1);
        a2 = MFMA(ax0h, wx0l, a2);
        a0 = MFMA(ax1h, wx1h, a0);
        a1 = MFMA(ax1l, wx1h, a1);
        a2 = MFMA(ax1h, wx1l, a2);
        a0 = MFMA(ah_h, whh_, a0);
        a1 = MFMA(ah_l, whh_, a1);
        a2 = MFMA(ah_h, whl_, a2);
        f32x4 acc = (a0 + a1) + a2;

        // nonlinearity (wave-uniform) + publish gates
#pragma unroll
        for (int r = 0; r < 4; ++r) {
            float v  = acc[r];
            float zx = is_tanh ? 2.0f * v : v;
            float s  = __builtin_amdgcn_rcpf(1.0f + __expf(-zx));
            float g  = is_tanh ? 2.0f * s - 1.0f : s;
            Gp[wid >> 1][kg * 4 + r][jw] = g;
        }
        __syncthreads();   // B: gates ready

        if (tid < 256) {
            // combine: one (b, j) cell per thread, c persistent
            float iv = Gp[0][cb][cj];
            float fv = Gp[1][cb][cj];
            float gv = Gp[2][cb][cj];
            float ov = Gp[3][cb][cj];
            cc = fmaf(fv, cc, iv * gv);
            float th = 2.0f * __builtin_amdgcn_rcpf(1.0f + __expf(-2.0f * cc)) - 1.0f;
            hlast = ov * th;
            unsigned p = pack_split(hlast);
            hh[cb][cj] = (unsigned short)(p >> 16);
            hl[cb][cj] = (unsigned short)(p & 0xFFFFu);
        } else if (t + 2 < S_) {
            // pack x[t+2] (waves 4..7, parallel with combine)
            unsigned p0 = pack_split(xnext.x), p1 = pack_split(xnext.y);
            const int s2 = (t + 2) & 3;
            *(unsigned*)&xh[s2][pr][pc] = (p0 >> 16) | (p1 & 0xFFFF0000u);
            *(unsigned*)&xl[s2][pr][pc] = (p0 & 0xFFFFu) | (p1 << 16);
        }
    }
    __syncthreads();

    // ---- MLP head: 32 -> 32 -> 16 -> 3, leaky_relu(0.01) ----
    float* Hb = &Gp[0][0][0];
    float* A1 = &Gp[1][0][0];
    float* A2 = &Gp[2][0][0];
    if (tid < 256) Hb[cb * GS + cj] = hlast;
    __syncthreads();
    if (tid < 256) {
        int rb = tid >> 5, n = tid & 31;
        float a = b1[n];
#pragma unroll
        for (int k = 0; k < 32; ++k) a = fmaf(Hb[rb * GS + k], W1[k * 32 + n], a);
        a = (a > 0.0f) ? a : 0.01f * a;
        A1[rb * GS + n] = a;
    }
    __syncthreads();
    if (tid < 128) {
        int rb = tid >> 4, n = tid & 15;
        float a = b2[n];
#pragma unroll
        for (int k = 0; k < 32; ++k) a = fmaf(A1[rb * GS + k], W2[k * 16 + n], a);
        a = (a > 0.0f) ? a : 0.01f * a;
        A2[rb * GS + n] = a;
    }
    __syncthreads();
    if (tid < 24) {
        int rb = tid / 3, n = tid - rb * 3;
        float a = bo[n];
#pragma unroll
        for (int k = 0; k < 16; ++k) a = fmaf(A2[rb * GS + k], Wo[k * 3 + n], a);
        out[(size_t)(bb + rb) * 3 + n] = a;
    }
}

extern "C" void kernel_launch(void* const* d_in, const int* in_sizes, int n_in,
                              void* d_out, int out_size, void* d_ws, size_t ws_size,
                              hipStream_t stream) {
    const float* x  = (const float*)d_in[0];
    const float* Wx = (const float*)d_in[1];
    const float* Wh = (const float*)d_in[2];
    const float* bg = (const float*)d_in[3];
    const float* W1 = (const float*)d_in[4];
    const float* b1 = (const float*)d_in[5];
    const float* W2 = (const float*)d_in[6];
    const float* b2 = (const float*)d_in[7];
    const float* Wo = (const float*)d_in[8];
    const float* bo = (const float*)d_in[9];
    float* out = (float*)d_out;

    hipLaunchKernelGGL(lstm_mfma_kernel, dim3(NB), dim3(512), 0, stream,
                       x, Wx, Wh, bg, W1, b1, W2, b2, Wo, bo, out);
}